// Round 6
// baseline (665.298 us; speedup 1.0000x reference)
//
#include <hip/hip_runtime.h>

typedef short short8 __attribute__((ext_vector_type(8)));
typedef float floatx4 __attribute__((ext_vector_type(4)));

__device__ __forceinline__ unsigned short f2bf(float x) {
  union { float f; unsigned int u; } c; c.f = x;
  return (unsigned short)((c.u + 0x7FFFu + ((c.u >> 16) & 1u)) >> 16);
}

__device__ __forceinline__ unsigned cvtpk(float lo, float hi) {
  unsigned r;
  asm("v_cvt_pk_bf16_f32 %0, %1, %2" : "=v"(r) : "v"(lo), "v"(hi));
  return r;
}

__device__ __forceinline__ void gld16(const void* g, void* l) {
  __builtin_amdgcn_global_load_lds((const __attribute__((address_space(1))) void*)g,
                                   (__attribute__((address_space(3))) void*)l, 16, 0, 0);
}

__global__ void k_hist(const int* __restrict__ gid, int L, int* __restrict__ counts) {
  int i = blockIdx.x * blockDim.x + threadIdx.x;
  if (i < L) atomicAdd(&counts[gid[i]], 1);
}

__global__ void k_scan(const int* __restrict__ counts, int* __restrict__ offsets,
                       int* __restrict__ cursor, int G) {
  __shared__ int sc[1024];
  int t = threadIdx.x;
  int items = (G + 1023) >> 10;
  int base = t * items;
  int s = 0;
  for (int i = 0; i < items; ++i) { int idx = base + i; if (idx < G) s += counts[idx]; }
  sc[t] = s;
  __syncthreads();
  for (int off = 1; off < 1024; off <<= 1) {
    int v = (t >= off) ? sc[t - off] : 0;
    __syncthreads();
    if (t >= off) sc[t] += v;
    __syncthreads();
  }
  int run = (t == 0) ? 0 : sc[t - 1];
  for (int i = 0; i < items; ++i) {
    int idx = base + i;
    if (idx < G) { offsets[idx] = run; cursor[idx] = run; run += counts[idx]; }
  }
  if (t == 1023) offsets[G] = sc[1023];
}

__global__ void k_scatter(const int* __restrict__ gid, int L, int* __restrict__ cursor,
                          int* __restrict__ order, int* __restrict__ gids) {
  int i = blockIdx.x * blockDim.x + threadIdx.x;
  if (i < L) {
    int g = gid[i];
    int pos = atomicAdd(&cursor[g], 1);
    order[pos] = i;
    gids[pos] = g;
  }
}

// W2 [512][256] bf16 (4-wave layout): row j2 = 128*w + 64*half + c -> d = 64*w + c
// (half 0 = key, 1 = value). Wave w's 128 rows cover its 64-col d-range for BOTH proj.
__global__ void k_prepw(const float* __restrict__ keyW, const float* __restrict__ valW,
                        unsigned short* __restrict__ W2) {
  int j2 = blockIdx.x;
  int k = threadIdx.x;
  int wv = j2 >> 7, half = (j2 >> 6) & 1, c = j2 & 63;
  int d = (wv << 6) + c;
  const float* src = half ? valW : keyW;
  W2[j2 * 256 + k] = f2bf(src[d * 256 + k]);
}

// One block per 32 consecutive sorted rows. Gather -> MFMA -> per-run reduce ->
// f32 atomicAdd partials into dn[g][0:256]=den, dn[g][256:512]=num.
__launch_bounds__(256, 4)
__global__ void k_gp(const float* __restrict__ fnode,
                     const unsigned short* __restrict__ W2,
                     const float* __restrict__ key_b, const float* __restrict__ value_b,
                     const int* __restrict__ order, const int* __restrict__ gids,
                     float* __restrict__ dn, int L) {
  // 32 rows x 1KB f32, gll-filled; LDS 16B-slot s of row r holds global slot s^(r&7)
  __shared__ __align__(16) float As[32 * 256];
  __shared__ int ord_s[32];
  __shared__ int gid_s[32];

  const int t = threadIdx.x;
  const int lane = t & 63;
  const int w = t >> 6;        // wave 0..3 -> d range [64w, 64w+64)
  const int lcol = lane & 15;
  const int lrow = lane >> 4;
  const int r0 = blockIdx.x << 5;
  const int nvalid = min(32, L - r0);

  if (t < 32) ord_s[t] = order[min(r0 + t, L - 1)];
  else if (t < 64) gid_s[t - 32] = (r0 + t - 32 < L) ? gids[r0 + t - 32] : -1;
  __syncthreads();

  // ---- gather: wave w stages rows [8w, 8w+8), one gll (1KB row) each ----
#pragma unroll
  for (int it = 0; it < 8; ++it) {
    const int rowl = (w << 3) + it;          // rowl & 7 == it
    const int idx = ord_s[rowl];
    const char* gsrc =
        (const char*)fnode + ((size_t)idx << 10) + ((lane << 4) ^ (it << 4));
    gld16(gsrc, (char*)As + (rowl << 10));
  }

  // overlaps the gather:
  float kb[4], vb[4];
#pragma unroll
  for (int nj = 0; nj < 4; ++nj) {
    int d = (w << 6) + (nj << 4) + lcol;
    kb[nj] = key_b[d];
    vb[nj] = value_b[d];
  }
  const unsigned short* Wb = W2 + ((size_t)((w << 7) + lcol)) * 256 + lrow * 8;

  asm volatile("s_waitcnt vmcnt(0)" ::: "memory");
  __syncthreads();

  // ---- MFMA: A[32x256] x W2w[128x256]^T -> acc[2 mi][8 nj] ----
  floatx4 acc[2][8];
#pragma unroll
  for (int mi = 0; mi < 2; ++mi)
#pragma unroll
    for (int nj = 0; nj < 8; ++nj)
      acc[mi][nj] = (floatx4){0.f, 0.f, 0.f, 0.f};

  __builtin_amdgcn_s_setprio(1);
#pragma unroll
  for (int kk = 0; kk < 8; ++kk) {
    short8 afr[2];
#pragma unroll
    for (int mi = 0; mi < 2; ++mi) {
      const int row = mi * 16 + lcol;
      const char* rbase = (const char*)As + (row << 10);
      const int s0 = (kk * 8 + lrow * 2) ^ (row & 7);
      const int s1 = (kk * 8 + lrow * 2 + 1) ^ (row & 7);
      const floatx4 lo = *reinterpret_cast<const floatx4*>(rbase + (s0 << 4));
      const floatx4 hi = *reinterpret_cast<const floatx4*>(rbase + (s1 << 4));
      union { unsigned u[4]; short8 s; } cc;
      cc.u[0] = cvtpk(lo[0], lo[1]);
      cc.u[1] = cvtpk(lo[2], lo[3]);
      cc.u[2] = cvtpk(hi[0], hi[1]);
      cc.u[3] = cvtpk(hi[2], hi[3]);
      afr[mi] = cc.s;
    }
#pragma unroll
    for (int nj = 0; nj < 8; ++nj) {
      const short8 bfr =
          *reinterpret_cast<const short8*>(Wb + (size_t)nj * 4096 + kk * 32);
#pragma unroll
      for (int mi = 0; mi < 2; ++mi)
        acc[mi][nj] =
            __builtin_amdgcn_mfma_f32_16x16x32_bf16(afr[mi], bfr, acc[mi][nj], 0, 0, 0);
    }
  }
  __builtin_amdgcn_s_setprio(0);

  // ---- per-run reduce + atomic partials. nj 0-3 attn, nj+4 val at same (r,d) ----
  const bool isStart =
      (lane < nvalid) && (lane == 0 || gid_s[lane] != gid_s[lane - 1]);
  unsigned long long bm = __ballot(isStart);
  while (bm) {
    const int rlo = __ffsll((unsigned long long)bm) - 1;
    const unsigned long long rest = bm & (bm - 1);
    const int rhi = rest ? (__ffsll((unsigned long long)rest) - 1) : nvalid;
    const int gg = gid_s[rlo];
#pragma unroll
    for (int nj = 0; nj < 4; ++nj) {
      float de = 0.f, nu = 0.f;
#pragma unroll
      for (int mi = 0; mi < 2; ++mi)
#pragma unroll
        for (int qq = 0; qq < 4; ++qq) {
          const int r = mi * 16 + lrow * 4 + qq;
          const bool in = (r >= rlo) && (r < rhi);
          const float a = acc[mi][nj][qq] + kb[nj];
          const float v = acc[mi][nj + 4][qq] + vb[nj];
          const float e = in ? __expf(a) : 0.f;
          de += e;
          nu += v * e;
        }
      de += __shfl_xor(de, 16, 64);
      de += __shfl_xor(de, 32, 64);
      nu += __shfl_xor(nu, 16, 64);
      nu += __shfl_xor(nu, 32, 64);
      if (lrow == 0) {
        const int d = (w << 6) + (nj << 4) + lcol;
        atomicAdd(&dn[(size_t)gg * 512 + d], de);
        atomicAdd(&dn[(size_t)gg * 512 + 256 + d], nu);
      }
    }
    bm = rest;
  }
}

__global__ void k_finish(const float* __restrict__ dn, const float* __restrict__ gamma,
                         const float* __restrict__ beta, float* __restrict__ out) {
  __shared__ float redS[4], redS2[4];
  const int g = blockIdx.x;
  const int t = threadIdx.x;
  const int lane = t & 63;
  const int w = t >> 6;
  const float de = dn[(size_t)g * 512 + t];
  const float nu = dn[(size_t)g * 512 + 256 + t];
  const float x = nu / (de + 1e-7f);
  float s = x, s2 = x * x;
#pragma unroll
  for (int o = 32; o > 0; o >>= 1) {
    s += __shfl_xor(s, o, 64);
    s2 += __shfl_xor(s2, o, 64);
  }
  if (lane == 0) { redS[w] = s; redS2[w] = s2; }
  __syncthreads();
  const float ts = redS[0] + redS[1] + redS[2] + redS[3];
  const float ts2 = redS2[0] + redS2[1] + redS2[2] + redS2[3];
  const float mu = ts * (1.f / 256.f);
  const float var = ts2 * (1.f / 256.f) - mu * mu;
  const float inv = rsqrtf(var + 1e-5f);
  out[(size_t)g * 256 + t] = (x - mu) * inv * gamma[t] + beta[t];
}

extern "C" void kernel_launch(void* const* d_in, const int* in_sizes, int n_in,
                              void* d_out, int out_size, void* d_ws, size_t ws_size,
                              hipStream_t stream) {
  const float* f_node   = (const float*)d_in[0];
  const float* key_W    = (const float*)d_in[1];
  const float* key_b    = (const float*)d_in[2];
  const float* value_W  = (const float*)d_in[3];
  const float* value_b  = (const float*)d_in[4];
  const float* gamma    = (const float*)d_in[5];
  const float* beta     = (const float*)d_in[6];
  const int*   graph_id = (const int*)d_in[7];
  const int L = in_sizes[0] / 256;
  const int G = out_size / 256;

  char* ws = (char*)d_ws;
  size_t off = 0;
  int* order = (int*)(ws + off); off += (size_t)L * 4;
  int* gids  = (int*)(ws + off); off += (size_t)L * 4;
  off = (off + 255) & ~(size_t)255;
  int* counts = (int*)(ws + off); off += (size_t)G * 4;
  int* offsets = (int*)(ws + off); off += (size_t)(G + 1) * 4;
  int* cursor = (int*)(ws + off); off += (size_t)G * 4;
  off = (off + 255) & ~(size_t)255;
  unsigned short* W2 = (unsigned short*)(ws + off); off += 512 * 256 * 2;
  off = (off + 255) & ~(size_t)255;
  float* dn = (float*)(ws + off); off += (size_t)G * 512 * 4;

  hipMemsetAsync(counts, 0, (size_t)G * 4, stream);
  hipMemsetAsync(dn, 0, (size_t)G * 512 * 4, stream);
  k_hist<<<(L + 255) / 256, 256, 0, stream>>>(graph_id, L, counts);
  k_scan<<<1, 1024, 0, stream>>>(counts, offsets, cursor, G);
  k_scatter<<<(L + 255) / 256, 256, 0, stream>>>(graph_id, L, cursor, order, gids);
  k_prepw<<<512, 256, 0, stream>>>(key_W, value_W, W2);
  k_gp<<<(L + 31) / 32, 256, 0, stream>>>(f_node, W2, key_b, value_b, order, gids, dn, L);
  k_finish<<<G, 256, 0, stream>>>(dn, gamma, beta, (float*)d_out);
}